// Round 3
// baseline (3921.572 us; speedup 1.0000x reference)
//
#include <hip/hip_runtime.h>
#include <hip/hip_bf16.h>

typedef __hip_bfloat16 bf16;

__device__ __forceinline__ float bf2f(bf16 x) { return __bfloat162float(x); }

#define MASKED_SENTINEL (-1.0e30f)

// Inputs/outputs are FP32 (per the reference dtypes). One workgroup = one
// (batch, 8x8 block); loops over 8 heads, accumulating the output projection
// across heads in registers (no ws, no atomics).
//
// LDS arena (50176 B) phase-local views, all transitions barrier-separated:
//   P1/P2: s_xc [32][196] f32 (25088 B, offset 0) x-window chunk, 4 chunks/head
//   P3/P4: k_s  [196][64] bf16 (offset 0..25087)  k, later overwritten by p
//          v_s  [196][64] bf16 (offset 25088..50175)
//   P5:    outh [64][65]  f32  (offset 0, 16640 B over dead p)
//          wo_s [64][128] bf16 (offset 25088, 16384 B over dead v)
// Plus s_q [64][66] bf16 (8448 B), s_red [2][4][64] f32 (2048 B). Total 60672 B.
__global__ __launch_bounds__(256, 1)
void halo_attn_kernel(const float* __restrict__ xg,
                      const float* __restrict__ Wq,
                      const float* __restrict__ Wkv,
                      const float* __restrict__ Wo,
                      const float* __restrict__ bo,
                      float* __restrict__ outg)
{
    __shared__ __align__(16) char smem[50176];
    __shared__ bf16  s_q[64 * 66];
    __shared__ float s_red[2][4][64];

    float* s_xc = (float*)smem;           // [32][196] f32 chunk
    bf16*  k_s  = (bf16*)smem;            // [196][64] k then p
    bf16*  v_s  = (bf16*)(smem + 25088);  // [196][64]
    float* outh = (float*)smem;           // [64][65] f32
    bf16*  wo_s = (bf16*)(smem + 25088);  // [64][128]

    const int tid  = threadIdx.x;
    const int lane = tid & 63;
    const int sub  = tid >> 6;            // wave id 0..3 (wave-uniform)

    const int wg  = blockIdx.x;
    const int b   = wg >> 8;
    const int blk = wg & 255;
    const int by = blk >> 4, bx = blk & 15;
    const int y0 = by * 8 - 3, x0 = bx * 8 - 3;

    // res[m2]: out[i=lane][c=sub+4*m2], bias-initialized once.
    float res[32];
#pragma unroll
    for (int m2 = 0; m2 < 32; ++m2) res[m2] = bo[sub + 4 * m2];

    // query pixel i = sub+4*m sits at window slot (qy+3, qx+3)
    int jqr[16];
#pragma unroll
    for (int m = 0; m < 16; ++m) {
        int i = sub + 4 * m;
        jqr[m] = ((i >> 3) + 3) * 14 + (i & 7) + 3;
    }

    for (int h = 0; h < 8; ++h) {
        __syncthreads();   // previous head's readers of the arena are done

        // ---- Phase 1+2: stage x in 4 fp32 chunks, accumulate q/k/v in regs ----
        float kreg[49], vreg[49], qreg[16];
#pragma unroll
        for (int n = 0; n < 49; ++n) { kreg[n] = 0.f; vreg[n] = 0.f; }
#pragma unroll
        for (int m = 0; m < 16; ++m) qreg[m] = 0.f;

        for (int chunk = 0; chunk < 4; ++chunk) {
            const int c0 = chunk * 32;
            for (int t = tid; t < 32 * 196; t += 256) {
                int cl = t / 196;
                int j  = t - cl * 196;
                int wy = j / 14;
                int wx = j - wy * 14;
                int gy = y0 + wy, gx = x0 + wx;
                float v = 0.f;
                if ((unsigned)gy < 128u && (unsigned)gx < 128u)
                    v = xg[((b * 128 + c0 + cl) * 128 + gy) * 128 + gx];
                s_xc[t] = v;
            }
            __syncthreads();

            for (int cl = 0; cl < 32; ++cl) {
                int c = c0 + cl;
                float wq = Wq[c * 512 + h * 64 + lane];
                float wk = Wkv[c * 1024 + h * 64 + lane];
                float wv = Wkv[c * 1024 + 512 + h * 64 + lane];
                const float* xc = &s_xc[cl * 196];
#pragma unroll
                for (int n = 0; n < 49; ++n) {
                    float xv = xc[sub + 4 * n];    // wave-uniform addr: broadcast
                    kreg[n] = fmaf(xv, wk, kreg[n]);
                    vreg[n] = fmaf(xv, wv, vreg[n]);
                }
#pragma unroll
                for (int m = 0; m < 16; ++m)
                    qreg[m] = fmaf(xc[jqr[m]], wq, qreg[m]);
            }
            __syncthreads();   // chunk reads done before next chunk / k-v store
        }

        // ---- store q (scaled 1/8), k, v as bf16 ----
#pragma unroll
        for (int m = 0; m < 16; ++m)
            s_q[(sub + 4 * m) * 66 + lane] = __float2bfloat16(qreg[m] * 0.125f);
#pragma unroll
        for (int n = 0; n < 49; ++n) {
            int j = sub + 4 * n;
            k_s[j * 64 + lane] = __float2bfloat16(kreg[n]);
            v_s[j * 64 + lane] = __float2bfloat16(vreg[n]);
        }
        __syncthreads();

        // ---- Phase 3: sim + softmax. Thread owns row i=lane, cols j=sub+4*n ----
        float qr[64];
#pragma unroll
        for (int d = 0; d < 64; ++d) qr[d] = bf2f(s_q[lane * 66 + d]);

        float simr[49];
        float mx = MASKED_SENTINEL;
#pragma unroll 1
        for (int n = 0; n < 49; ++n) {
            int j = sub + 4 * n;
            int wy = j / 14;
            int wx = j - wy * 14;
            int gy = y0 + wy, gx = x0 + wx;
            bool ok = ((unsigned)gy < 128u) && ((unsigned)gx < 128u);
            float acc = MASKED_SENTINEL;
            if (ok) {      // wave-uniform (j uniform across the wave)
                acc = 0.f;
                const bf16* krow = &k_s[j * 64];
#pragma unroll
                for (int d = 0; d < 64; ++d)
                    acc = fmaf(qr[d], bf2f(krow[d]), acc);
            }
            simr[n] = acc;
            mx = fmaxf(mx, acc);
        }
        s_red[0][sub][lane] = mx;
        __syncthreads();
        float m0 = fmaxf(fmaxf(s_red[0][0][lane], s_red[0][1][lane]),
                         fmaxf(s_red[0][2][lane], s_red[0][3][lane]));
        float ssum = 0.f;
#pragma unroll
        for (int n = 0; n < 49; ++n) {
            float p = 0.f;
            if (simr[n] > -0.5e30f)          // never exponentiate the sentinel
                p = __expf(simr[n] - m0);    // arg <= 0 by construction
            simr[n] = p;
            ssum += p;
        }
        s_red[1][sub][lane] = ssum;
        __syncthreads();
        float stot = s_red[1][0][lane] + s_red[1][1][lane]
                   + s_red[1][2][lane] + s_red[1][3][lane];
        float rinv = (stot > 0.f) ? (1.f / stot) : 0.f;
        // normalized p overwrites k (all k reads finished before first barrier)
#pragma unroll
        for (int n = 0; n < 49; ++n) {
            int j = sub + 4 * n;
            k_s[j * 64 + lane] = __float2bfloat16(simr[n] * rinv);
        }
        __syncthreads();

        // ---- Phase 4: out_h = p @ v. Thread owns rows i=sub+4*m, col dv=lane ----
        float pout[16];
#pragma unroll
        for (int m = 0; m < 16; ++m) pout[m] = 0.f;
        const bf16* p_s = k_s;
#pragma unroll 1
        for (int j = 0; j < 196; ++j) {
            float vv = bf2f(v_s[j * 64 + lane]);
#pragma unroll
            for (int m = 0; m < 16; ++m)
                pout[m] = fmaf(bf2f(p_s[j * 64 + sub + 4 * m]), vv, pout[m]);
        }
        __syncthreads();   // p and v now dead

#pragma unroll
        for (int m = 0; m < 16; ++m)
            outh[(sub + 4 * m) * 65 + lane] = pout[m];
        for (int t = tid; t < 64 * 128; t += 256)
            wo_s[t] = __float2bfloat16(Wo[h * 64 * 128 + t]);
        __syncthreads();

        // ---- Phase 5: res += out_h @ Wo_h. Thread: row i=lane, cols c=sub+4*m2 ----
#pragma unroll 1
        for (int dd = 0; dd < 64; ++dd) {
            float ow = outh[lane * 65 + dd];
#pragma unroll
            for (int m2 = 0; m2 < 32; ++m2)
                res[m2] = fmaf(ow, bf2f(wo_s[dd * 128 + sub + 4 * m2]), res[m2]);
        }
    } // heads

    // ---- store fp32: out[b][c][by*8+py][bx*8+px], i = lane ----
    {
        int py = lane >> 3, px = lane & 7;
        int gy = by * 8 + py, gx = bx * 8 + px;
#pragma unroll
        for (int m2 = 0; m2 < 32; ++m2) {
            int c = sub + 4 * m2;
            outg[((b * 128 + c) * 128 + gy) * 128 + gx] = res[m2];
        }
    }
}

extern "C" void kernel_launch(void* const* d_in, const int* in_sizes, int n_in,
                              void* d_out, int out_size, void* d_ws, size_t ws_size,
                              hipStream_t stream) {
    const float* x   = (const float*)d_in[0];
    const float* Wq  = (const float*)d_in[1];
    const float* Wkv = (const float*)d_in[2];
    const float* Wo  = (const float*)d_in[3];
    const float* bo  = (const float*)d_in[4];
    float* out = (float*)d_out;
    hipLaunchKernelGGL(halo_attn_kernel, dim3(4 * 256), dim3(256), 0, stream,
                       x, Wq, Wkv, Wo, bo, out);
}

// Round 4
// 422.735 us; speedup vs baseline: 9.2767x; 9.2767x over previous
//
#include <hip/hip_runtime.h>
#include <hip/hip_bf16.h>

typedef unsigned short ushort_t;
typedef __attribute__((ext_vector_type(8))) short short8;
typedef __attribute__((ext_vector_type(4))) short short4v;
typedef __attribute__((ext_vector_type(4))) float float4v;

__device__ __forceinline__ unsigned short f2b(float f) {  // RNE f32->bf16 bits
    unsigned int u = __float_as_uint(f);
    return (unsigned short)((u + 0x7fffu + ((u >> 16) & 1u)) >> 16);
}

#define MFMA(a, b, c) __builtin_amdgcn_mfma_f32_16x16x32_bf16((a), (b), (c), 0, 0, 0)

// ws layout (bf16): wqt[512][128] = Wq^T | wkvt[8][128][128] = per-head [Wk_h^T; Wv_h^T]
// | wot[128][512] = Wo^T.  All are B-operands (B^T row-major, contiguous K).
__global__ void prep_weights(const float* __restrict__ Wq,
                             const float* __restrict__ Wkv,
                             const float* __restrict__ Wo,
                             ushort_t* __restrict__ ws)
{
    int t = blockIdx.x * 256 + threadIdx.x;   // 262144 total
    if (t < 65536) {
        int n = t >> 7, c = t & 127;
        ws[t] = f2b(Wq[c * 512 + n]);
    } else if (t < 196608) {
        int u = t - 65536;
        int h = u >> 14, r = (u >> 7) & 127, c = u & 127;
        float v = (r < 64) ? Wkv[c * 1024 + h * 64 + r]
                           : Wkv[c * 1024 + 512 + h * 64 + (r - 64)];
        ws[t] = f2b(v);
    } else {
        int u = t - 196608;
        int c = u >> 9, n = u & 511;
        ws[t] = f2b(Wo[n * 128 + c]);
    }
}

// LDS (dynamic, 156160 B): strides are 16B multiples; bank shift 4 (or 20) per
// row => <=2-way conflicts (free).
//   s_x  [208][136] @0       56576 B   x window bf16, rows 196..207 zero
//   k_s  [208][72]  @56576   29952 B   k[j][d]   (o_s[64][72] aliases base)
//   v_t  [64][232]  @86528   29696 B   v^T[dv][j], cols 208..231 zero
//   p_s  [64][232]  @116224  29696 B   exp(sim)[i][j], cols 208..231 zero
//   q_s  [64][72]   @145920   9216 B   q[i][d] (pre-scaled by 1/8)
//   s_max[2][64]    @155136    512 B ; s_sum[2][64] @155648 512 B
__global__ __launch_bounds__(512, 2)
void halo_attn_mfma(const float* __restrict__ xg,
                    const ushort_t* __restrict__ wqt,
                    const ushort_t* __restrict__ wkvt,
                    const ushort_t* __restrict__ wot,
                    const float* __restrict__ bo,
                    float* __restrict__ outg)
{
    extern __shared__ char smem[];
    ushort_t* s_x   = (ushort_t*)(smem);
    ushort_t* k_s   = (ushort_t*)(smem + 56576);
    ushort_t* v_t   = (ushort_t*)(smem + 86528);
    ushort_t* p_s   = (ushort_t*)(smem + 116224);
    ushort_t* q_s   = (ushort_t*)(smem + 145920);
    float*    s_max = (float*)(smem + 155136);
    float*    s_sum = (float*)(smem + 155648);
    ushort_t* o_s   = k_s;    // alias: k dead after S, o written in PV

    const int tid  = threadIdx.x;
    const int w    = tid >> 6;       // wave 0..7
    const int lane = tid & 63;
    const int m    = lane & 15;      // MFMA col / A-row lane
    const int quad = lane >> 4;      // MFMA k-group / C row-group

    const int wg  = blockIdx.x;
    const int b   = wg >> 8;
    const int blk = wg & 255;
    const int by = blk >> 4, bx = blk & 15;
    const int y0 = by * 8 - 3, x0 = bx * 8 - 3;

    // ---- init: zero j-pads of p_s/v_t, stage x window, zero x rows 196..207 ----
    for (int t = tid; t < 64 * 24; t += 512) {
        int r = t / 24, c = 208 + (t - r * 24);
        p_s[r * 232 + c] = 0;
        v_t[r * 232 + c] = 0;
    }
    for (int t = tid; t < 128 * 256; t += 512) {
        int c = t >> 8, wy = (t >> 4) & 15, wx = t & 15;
        if (wy < 14 && wx < 14) {
            int gy = y0 + wy, gx = x0 + wx;
            float v = 0.f;
            if ((unsigned)gy < 128u && (unsigned)gx < 128u)
                v = xg[((b * 128 + c) * 128 + gy) * 128 + gx];
            s_x[(wy * 14 + wx) * 136 + c] = f2b(v);
        }
    }
    for (int t = tid; t < 12 * 128; t += 512)
        s_x[(196 + (t >> 7)) * 136 + (t & 127)] = 0;
    __syncthreads();

    float4v res[4];
#pragma unroll
    for (int i = 0; i < 4; ++i) res[i] = (float4v){0.f, 0.f, 0.f, 0.f};

    for (int h = 0; h < 8; ++h) {
        // ===== P-kv: [208,128] @ [128,128] -> k_s / v_t. wave: fixed nt = w&7 =====
        {
            const int nt = w & 7;
            const ushort_t* bb = wkvt + h * 16384 + (nt * 16 + m) * 128 + quad * 8;
            short8 bfr[4];
#pragma unroll
            for (int kk = 0; kk < 4; ++kk) bfr[kk] = *(const short8*)(bb + kk * 32);
#pragma unroll 1
            for (int jt = 0; jt < 13; ++jt) {
                float4v c = {0.f, 0.f, 0.f, 0.f};
                const ushort_t* ar = s_x + (jt * 16 + m) * 136 + quad * 8;
#pragma unroll
                for (int kk = 0; kk < 4; ++kk) {
                    short8 af = *(const short8*)(ar + kk * 32);
                    c = MFMA(af, bfr[kk], c);
                }
                if (nt < 4) {                       // k: rows j, cols d
                    int d = nt * 16 + m;
#pragma unroll
                    for (int r = 0; r < 4; ++r)
                        k_s[(jt * 16 + quad * 4 + r) * 72 + d] = f2b(c[r]);
                } else {                            // v^T: row dv, 4 consecutive j
                    int dv = (nt - 4) * 16 + m;
                    short4v pk;
#pragma unroll
                    for (int r = 0; r < 4; ++r) pk[r] = (short)f2b(c[r]);
                    *(short4v*)(v_t + dv * 232 + jt * 16 + quad * 4) = pk;
                }
            }
        }
        // ===== P-q: [64,128] @ [128,64] -> q_s (A-rows via interior-pixel map) =====
        {
            const int nt = w & 3;
            const ushort_t* bb = wqt + (h * 64 + nt * 16 + m) * 128 + quad * 8;
            short8 bfr[4];
#pragma unroll
            for (int kk = 0; kk < 4; ++kk) bfr[kk] = *(const short8*)(bb + kk * 32);
#pragma unroll
            for (int tt = 0; tt < 2; ++tt) {
                int it = (w >> 2) + tt * 2;
                float4v c = {0.f, 0.f, 0.f, 0.f};
                int i = it * 16 + m;
                int jq = ((i >> 3) + 3) * 14 + (i & 7) + 3;
                const ushort_t* ar = s_x + jq * 136 + quad * 8;
#pragma unroll
                for (int kk = 0; kk < 4; ++kk) {
                    short8 af = *(const short8*)(ar + kk * 32);
                    c = MFMA(af, bfr[kk], c);
                }
                int d = nt * 16 + m;
#pragma unroll
                for (int r = 0; r < 4; ++r)
                    q_s[(it * 16 + quad * 4 + r) * 72 + d] = f2b(c[r] * 0.125f);
            }
        }
        __syncthreads();   // barrier 1: P writes visible

        // ===== S: sim = q @ k^T, two j-halves, softmax stats via shfl + LDS =====
        {
            const int it = w & 3;
            const int half = w >> 2;
            const int jt0 = half ? 7 : 0;
            const int ntile = half ? 6 : 7;
            short8 aq[2];
#pragma unroll
            for (int kk = 0; kk < 2; ++kk)
                aq[kk] = *(const short8*)(q_s + (it * 16 + m) * 72 + kk * 32 + quad * 8);
            float sc[7][4];
            int okm = 0;
            float pm[4] = {-3.0e38f, -3.0e38f, -3.0e38f, -3.0e38f};
#pragma unroll
            for (int u = 0; u < 7; ++u) {
                if (u < ntile) {
                    int jt = jt0 + u;
                    float4v c = {0.f, 0.f, 0.f, 0.f};
#pragma unroll
                    for (int kk = 0; kk < 2; ++kk) {
                        short8 bk = *(const short8*)(k_s + (jt * 16 + m) * 72 + kk * 32 + quad * 8);
                        c = MFMA(aq[kk], bk, c);
                    }
                    int j = jt * 16 + m;
                    bool ok = false;
                    if (j < 196) {
                        int wy = j / 14, wx = j - wy * 14;
                        ok = ((unsigned)(y0 + wy) < 128u) && ((unsigned)(x0 + wx) < 128u);
                    }
                    if (ok) {
                        okm |= (1 << u);
#pragma unroll
                        for (int r = 0; r < 4; ++r) pm[r] = fmaxf(pm[r], c[r]);
                    }
#pragma unroll
                    for (int r = 0; r < 4; ++r) sc[u][r] = c[r];
                }
            }
#pragma unroll
            for (int mk = 1; mk < 16; mk <<= 1)
#pragma unroll
                for (int r = 0; r < 4; ++r)
                    pm[r] = fmaxf(pm[r], __shfl_xor(pm[r], mk, 64));
            if (m == 0) {
#pragma unroll
                for (int r = 0; r < 4; ++r)
                    s_max[half * 64 + it * 16 + quad * 4 + r] = pm[r];
            }
            __syncthreads();   // barrier 2: maxes visible
            float m0[4], sm[4];
#pragma unroll
            for (int r = 0; r < 4; ++r) {
                int i = it * 16 + quad * 4 + r;
                m0[r] = fmaxf(s_max[i], s_max[64 + i]);
                sm[r] = 0.f;
            }
#pragma unroll
            for (int u = 0; u < 7; ++u) {
                if (u < ntile) {
                    int j = (jt0 + u) * 16 + m;
                    bool ok = (okm >> u) & 1;
#pragma unroll
                    for (int r = 0; r < 4; ++r) {
                        float p = ok ? __expf(sc[u][r] - m0[r]) : 0.f;
                        sm[r] += p;
                        p_s[(it * 16 + quad * 4 + r) * 232 + j] = f2b(p);
                    }
                }
            }
#pragma unroll
            for (int mk = 1; mk < 16; mk <<= 1)
#pragma unroll
                for (int r = 0; r < 4; ++r)
                    sm[r] += __shfl_xor(sm[r], mk, 64);
            if (m == 0) {
#pragma unroll
                for (int r = 0; r < 4; ++r)
                    s_sum[half * 64 + it * 16 + quad * 4 + r] = sm[r];
            }
            __syncthreads();   // barrier 3: p_s + sums visible; k_s now dead
        }

        // ===== PV: o = p @ v  (K = 224, zero-padded), normalize, -> o_s =====
        {
            const int nt = w & 3;
#pragma unroll
            for (int tt = 0; tt < 2; ++tt) {
                int it = (w >> 2) + tt * 2;
                float4v c = {0.f, 0.f, 0.f, 0.f};
                const ushort_t* ar = p_s + (it * 16 + m) * 232 + quad * 8;
                const ushort_t* br = v_t + (nt * 16 + m) * 232 + quad * 8;
#pragma unroll
                for (int kk = 0; kk < 7; ++kk) {
                    short8 af = *(const short8*)(ar + kk * 32);
                    short8 bf = *(const short8*)(br + kk * 32);
                    c = MFMA(af, bf, c);
                }
#pragma unroll
                for (int r = 0; r < 4; ++r) {
                    int i = it * 16 + quad * 4 + r;
                    float rv = 1.f / (s_sum[i] + s_sum[64 + i]);
                    o_s[i * 72 + nt * 16 + m] = f2b(c[r] * rv);
                }
            }
        }
        __syncthreads();   // barrier 4: o_s visible

        // ===== E: res += o @ Wo_h  (C-regs persist across heads) =====
        {
            const int ct = w & 7;
            const ushort_t* bb = wot + (ct * 16 + m) * 512 + h * 64 + quad * 8;
            short8 bw[2];
#pragma unroll
            for (int kk = 0; kk < 2; ++kk) bw[kk] = *(const short8*)(bb + kk * 32);
#pragma unroll
            for (int it = 0; it < 4; ++it) {
                float4v c = res[it];
                const ushort_t* ar = o_s + (it * 16 + m) * 72 + quad * 8;
#pragma unroll
                for (int kk = 0; kk < 2; ++kk) {
                    short8 af = *(const short8*)(ar + kk * 32);
                    c = MFMA(af, bw[kk], c);
                }
                res[it] = c;
            }
        }
        __syncthreads();   // barrier 5: o_s reads done before next head's P
    } // heads

    // ---- final: res + bias -> out[b][c][y][x] (fp32) ----
    {
        const int cch = (w & 7) * 16 + m;
        const float bias = bo[cch];
#pragma unroll
        for (int it = 0; it < 4; ++it) {
#pragma unroll
            for (int r = 0; r < 4; ++r) {
                int i = it * 16 + quad * 4 + r;
                int gy = by * 8 + (i >> 3), gx = bx * 8 + (i & 7);
                outg[((b * 128 + cch) * 128 + gy) * 128 + gx] = res[it][r] + bias;
            }
        }
    }
}

extern "C" void kernel_launch(void* const* d_in, const int* in_sizes, int n_in,
                              void* d_out, int out_size, void* d_ws, size_t ws_size,
                              hipStream_t stream) {
    const float* x   = (const float*)d_in[0];
    const float* Wq  = (const float*)d_in[1];
    const float* Wkv = (const float*)d_in[2];
    const float* Wo  = (const float*)d_in[3];
    const float* bo  = (const float*)d_in[4];
    float* out = (float*)d_out;
    ushort_t* ws = (ushort_t*)d_ws;   // needs 512 KB

    prep_weights<<<dim3(1024), dim3(256), 0, stream>>>(Wq, Wkv, Wo, ws);

    (void)hipFuncSetAttribute((const void*)halo_attn_mfma,
                              hipFuncAttributeMaxDynamicSharedMemorySize, 156160);
    halo_attn_mfma<<<dim3(1024), dim3(512), 156160, stream>>>(
        x, ws, ws + 65536, ws + 196608, bo, out);
}